// Round 1
// baseline (1985.922 us; speedup 1.0000x reference)
//
#include <hip/hip_runtime.h>
#include <stdint.h>

// ---------------------------------------------------------------------------
// GNN forward: GCN -> SAGE(+res) -> SAGE(+res) -> lin -> GCN
// Strategy: aggregate-first (linearity), CSR built once per call (no f32
// atomics in hot path), fused dense 64x64 GEMM epilogues.
// ---------------------------------------------------------------------------

__device__ __forceinline__ void fma4(float4& a, float s, const float4& w){
  a.x = fmaf(s, w.x, a.x);
  a.y = fmaf(s, w.y, a.y);
  a.z = fmaf(s, w.z, a.z);
  a.w = fmaf(s, w.w, a.w);
}

// ---------------- CSR build ----------------

__global__ __launch_bounds__(256) void k_deg(const int* __restrict__ dst,
                                             int* __restrict__ deg, int E){
  int i = blockIdx.x * 256 + threadIdx.x;
  if (i < E) atomicAdd(&deg[dst[i]], 1);
}

__global__ __launch_bounds__(256) void k_scanA(const int* __restrict__ deg,
                                               int* __restrict__ bsum, int n){
  __shared__ int sm[256];
  int b = blockIdx.x, t = threadIdx.x;
  int base = b * 1024 + t * 4;
  int s = 0;
  #pragma unroll
  for (int u = 0; u < 4; ++u){ int i = base + u; if (i < n) s += deg[i]; }
  sm[t] = s; __syncthreads();
  for (int off = 128; off > 0; off >>= 1){
    if (t < off) sm[t] += sm[t + off];
    __syncthreads();
  }
  if (t == 0) bsum[b] = sm[0];
}

__global__ void k_scanB(const int* __restrict__ bsum, int* __restrict__ bscan,
                        int* __restrict__ offs, int nb, int n){
  if (blockIdx.x == 0 && threadIdx.x == 0){
    int run = 0;
    for (int i = 0; i < nb; ++i){ bscan[i] = run; run += bsum[i]; }
    offs[n] = run;
  }
}

__global__ __launch_bounds__(256) void k_scanC(const int* __restrict__ deg,
                                               const int* __restrict__ bscan,
                                               int* __restrict__ offs, int n){
  __shared__ int sm[256];
  int b = blockIdx.x, t = threadIdx.x;
  int base = b * 1024 + t * 4;
  int v0 = (base + 0 < n) ? deg[base + 0] : 0;
  int v1 = (base + 1 < n) ? deg[base + 1] : 0;
  int v2 = (base + 2 < n) ? deg[base + 2] : 0;
  int v3 = (base + 3 < n) ? deg[base + 3] : 0;
  int ts = v0 + v1 + v2 + v3;
  sm[t] = ts; __syncthreads();
  #pragma unroll
  for (int off = 1; off < 256; off <<= 1){
    int add = (t >= off) ? sm[t - off] : 0;
    __syncthreads();
    sm[t] += add;
    __syncthreads();
  }
  int excl = sm[t] - ts;
  int run = bscan[b] + excl;
  if (base + 0 < n) offs[base + 0] = run; run += v0;
  if (base + 1 < n) offs[base + 1] = run; run += v1;
  if (base + 2 < n) offs[base + 2] = run; run += v2;
  if (base + 3 < n) offs[base + 3] = run; run += v3;
}

__global__ __launch_bounds__(256) void k_prep(const int* __restrict__ deg,
                                              float* __restrict__ dis,
                                              float* __restrict__ invd, int n){
  int i = blockIdx.x * 256 + threadIdx.x;
  if (i < n){
    float d = (float)deg[i];
    dis[i]  = rsqrtf(d + 1.0f);          // GCN: deg includes self-loop
    invd[i] = 1.0f / fmaxf(d, 1.0f);     // SAGE mean divisor
  }
}

__global__ __launch_bounds__(256) void k_fill(const int* __restrict__ src,
                                              const int* __restrict__ dst,
                                              const int* __restrict__ offs,
                                              int* __restrict__ cnt,
                                              int* __restrict__ csr, int E){
  int e = blockIdx.x * 256 + threadIdx.x;
  if (e < E){
    int d = dst[e];
    int p = offs[d] + atomicAdd(&cnt[d], 1);
    csr[p] = src[e];
  }
}

// ---------------- Aggregation (one wave per node, lane = feature) ----------
// MODE 0: GCN  out[i] = dis[i]*sum_j dis[j]*in[j] + dis[i]^2*in[i]
// MODE 1: SAGE out[i] = (sum_j in[j]) / max(deg,1)

template<int MODE>
__global__ __launch_bounds__(256) void k_agg(const float* __restrict__ in,
                                             const int* __restrict__ offs,
                                             const int* __restrict__ csr,
                                             const float* __restrict__ dis,
                                             const float* __restrict__ invd,
                                             float* __restrict__ out, int n){
  int node = (blockIdx.x * 256 + threadIdx.x) >> 6;
  if (node >= n) return;
  int lane = threadIdx.x & 63;
  int s = offs[node], e = offs[node + 1];
  float acc = 0.f;
  int k = s;
  for (; k + 4 <= e; k += 4){
    int j0 = csr[k], j1 = csr[k+1], j2 = csr[k+2], j3 = csr[k+3];
    float v0 = in[j0*64 + lane];
    float v1 = in[j1*64 + lane];
    float v2 = in[j2*64 + lane];
    float v3 = in[j3*64 + lane];
    if (MODE == 0){
      acc = fmaf(dis[j0], v0, acc);
      acc = fmaf(dis[j1], v1, acc);
      acc = fmaf(dis[j2], v2, acc);
      acc = fmaf(dis[j3], v3, acc);
    } else {
      acc += v0 + v1 + v2 + v3;
    }
  }
  for (; k < e; ++k){
    int j = csr[k];
    float v = in[j*64 + lane];
    acc += (MODE == 0) ? dis[j] * v : v;
  }
  float r;
  if (MODE == 0){
    float di = dis[node];
    r = di * acc + di * di * in[node*64 + lane];
  } else {
    r = acc * invd[node];
  }
  out[node*64 + lane] = r;
}

// ---------------- Dense 64x64 GEMM tiles ----------------
// 256 threads, 64-row tile, each thread computes a 4x4 block.
// A staged row-major in LDS with stride 68 (16B-aligned float4 rows, bank spread).

__device__ __forceinline__ void stage_A(const float* __restrict__ A,
                                        float (*As)[68], int row0, int n, int t){
  #pragma unroll
  for (int u = 0; u < 4; ++u){
    int q = u * 256 + t;
    int r = q >> 4;
    int c = (q & 15) * 4;
    int gr = row0 + r;
    float4 v = make_float4(0.f, 0.f, 0.f, 0.f);
    if (gr < n) v = *(const float4*)(A + (size_t)gr * 64 + c);
    *(float4*)&As[r][c] = v;
  }
}

__device__ __forceinline__ void stage_W(const float* __restrict__ W,
                                        float (*Ws)[64], int t){
  #pragma unroll
  for (int u = 0; u < 4; ++u){
    int q = u * 256 + t;
    int r = q >> 4;
    int c = (q & 15) * 4;
    *(float4*)&Ws[r][c] = *(const float4*)(W + r * 64 + c);
  }
}

__device__ __forceinline__ void tile_mm(const float (*As)[68], const float (*Ws)[64],
                                        float4 acc[4], int r0, int c0){
  #pragma unroll
  for (int k0 = 0; k0 < 64; k0 += 4){
    float4 a0 = *(const float4*)&As[r0+0][k0];
    float4 a1 = *(const float4*)&As[r0+1][k0];
    float4 a2 = *(const float4*)&As[r0+2][k0];
    float4 a3 = *(const float4*)&As[r0+3][k0];
    float4 w0 = *(const float4*)&Ws[k0+0][c0];
    float4 w1 = *(const float4*)&Ws[k0+1][c0];
    float4 w2 = *(const float4*)&Ws[k0+2][c0];
    float4 w3 = *(const float4*)&Ws[k0+3][c0];
    fma4(acc[0], a0.x, w0); fma4(acc[0], a0.y, w1); fma4(acc[0], a0.z, w2); fma4(acc[0], a0.w, w3);
    fma4(acc[1], a1.x, w0); fma4(acc[1], a1.y, w1); fma4(acc[1], a1.z, w2); fma4(acc[1], a1.w, w3);
    fma4(acc[2], a2.x, w0); fma4(acc[2], a2.y, w1); fma4(acc[2], a2.z, w2); fma4(acc[2], a2.w, w3);
    fma4(acc[3], a3.x, w0); fma4(acc[3], a3.y, w1); fma4(acc[3], a3.z, w2); fma4(acc[3], a3.w, w3);
  }
}

// out = act(A @ W + bias)
template<bool RELU>
__global__ __launch_bounds__(256) void k_gemm1(const float* __restrict__ A,
                                               const float* __restrict__ W,
                                               const float* __restrict__ bias,
                                               float* __restrict__ out, int n){
  __shared__ __align__(16) float As[64][68];
  __shared__ __align__(16) float Ws[64][64];
  int t = threadIdx.x;
  int row0 = blockIdx.x * 64;
  stage_W(W, Ws, t);
  stage_A(A, As, row0, n, t);
  __syncthreads();
  int r0 = (t >> 4) * 4, c0 = (t & 15) * 4;
  float4 b4 = *(const float4*)(bias + c0);
  float4 acc[4] = {b4, b4, b4, b4};
  tile_mm(As, Ws, acc, r0, c0);
  #pragma unroll
  for (int i = 0; i < 4; ++i){
    int gr = row0 + r0 + i;
    if (gr < n){
      float4 v = acc[i];
      if (RELU){
        v.x = fmaxf(v.x, 0.f); v.y = fmaxf(v.y, 0.f);
        v.z = fmaxf(v.z, 0.f); v.w = fmaxf(v.w, 0.f);
      }
      *(float4*)(out + (size_t)gr * 64 + c0) = v;
    }
  }
}

// out = act(A @ W1 + B @ W2 + bias + B)   (SAGE layer with residual)
template<bool RELU>
__global__ __launch_bounds__(256) void k_gemm_dual(const float* __restrict__ A,
                                                   const float* __restrict__ B,
                                                   const float* __restrict__ W1,
                                                   const float* __restrict__ W2,
                                                   const float* __restrict__ bias,
                                                   float* __restrict__ out, int n){
  __shared__ __align__(16) float As[64][68];
  __shared__ __align__(16) float Ws1[64][64];
  __shared__ __align__(16) float Ws2[64][64];
  int t = threadIdx.x;
  int row0 = blockIdx.x * 64;
  stage_W(W1, Ws1, t);
  stage_W(W2, Ws2, t);
  stage_A(A, As, row0, n, t);
  __syncthreads();
  int r0 = (t >> 4) * 4, c0 = (t & 15) * 4;
  float4 b4 = *(const float4*)(bias + c0);
  float4 acc[4] = {b4, b4, b4, b4};
  tile_mm(As, Ws1, acc, r0, c0);
  __syncthreads();
  stage_A(B, As, row0, n, t);
  __syncthreads();
  tile_mm(As, Ws2, acc, r0, c0);
  #pragma unroll
  for (int i = 0; i < 4; ++i){
    float4 res = *(const float4*)&As[r0 + i][c0];   // B tile still in LDS
    acc[i].x += res.x; acc[i].y += res.y; acc[i].z += res.z; acc[i].w += res.w;
    if (RELU){
      acc[i].x = fmaxf(acc[i].x, 0.f); acc[i].y = fmaxf(acc[i].y, 0.f);
      acc[i].z = fmaxf(acc[i].z, 0.f); acc[i].w = fmaxf(acc[i].w, 0.f);
    }
    int gr = row0 + r0 + i;
    if (gr < n) *(float4*)(out + (size_t)gr * 64 + c0) = acc[i];
  }
}

// ---------------------------------------------------------------------------

extern "C" void kernel_launch(void* const* d_in, const int* in_sizes, int n_in,
                              void* d_out, int out_size, void* d_ws, size_t ws_size,
                              hipStream_t stream){
  const float* x        = (const float*)d_in[0];
  const int*   ei       = (const int*)  d_in[1];
  const float* gcn1_w   = (const float*)d_in[2];
  const float* gcn1_b   = (const float*)d_in[3];
  const float* sage1_lw = (const float*)d_in[4];
  const float* sage1_lb = (const float*)d_in[5];
  const float* sage1_rw = (const float*)d_in[6];
  const float* sage2_lw = (const float*)d_in[7];
  const float* sage2_lb = (const float*)d_in[8];
  const float* sage2_rw = (const float*)d_in[9];
  const float* lin_w    = (const float*)d_in[10];
  const float* lin_b    = (const float*)d_in[11];
  const float* gcn2_w   = (const float*)d_in[12];
  const float* gcn2_b   = (const float*)d_in[13];
  float* out = (float*)d_out;

  const int n = in_sizes[0] / 64;
  const int E = in_sizes[1] / 2;
  const int* src = ei;
  const int* dst = ei + E;

  // workspace carve (~58 MB)
  uintptr_t p = (uintptr_t)d_ws;
  auto alloc = [&](size_t b) -> void* {
    p = (p + 255) & ~(uintptr_t)255;
    void* r = (void*)p; p += b; return r;
  };
  float* bufA = (float*)alloc((size_t)n * 64 * 4);
  float* bufB = (float*)alloc((size_t)n * 64 * 4);
  int*   deg  = (int*)  alloc((size_t)n * 4);
  int*   cnt  = (int*)  alloc((size_t)n * 4);
  int*   offs = (int*)  alloc((size_t)(n + 1) * 4);
  const int NB = (n + 1023) / 1024;
  int*   bsum  = (int*) alloc((size_t)NB * 4);
  int*   bscan = (int*) alloc((size_t)NB * 4);
  int*   csr   = (int*) alloc((size_t)E * 4);
  float* dis   = (float*)alloc((size_t)n * 4);
  float* invd  = (float*)alloc((size_t)n * 4);

  hipMemsetAsync(deg, 0, (size_t)n * 4, stream);
  hipMemsetAsync(cnt, 0, (size_t)n * 4, stream);

  const int gE = (E + 255) / 256;
  const int gN = (n + 255) / 256;
  const int gAgg = (n + 3) / 4;      // one wave per node, 4 waves/block
  const int gG = (n + 63) / 64;      // 64-row GEMM tiles

  // CSR build (shared by all 4 aggregation passes)
  k_deg  <<<gE, 256, 0, stream>>>(dst, deg, E);
  k_scanA<<<NB, 256, 0, stream>>>(deg, bsum, n);
  k_scanB<<<1, 1, 0, stream>>>(bsum, bscan, offs, NB, n);
  k_scanC<<<NB, 256, 0, stream>>>(deg, bscan, offs, n);
  k_prep <<<gN, 256, 0, stream>>>(deg, dis, invd, n);
  k_fill <<<gE, 256, 0, stream>>>(src, dst, offs, cnt, csr, E);

  // Layer 1: h1 = relu(GCNagg(x) @ gcn1_w + b)           -> d_out
  k_agg<0><<<gAgg, 256, 0, stream>>>(x, offs, csr, dis, invd, bufA, n);
  k_gemm1<true><<<gG, 256, 0, stream>>>(bufA, gcn1_w, gcn1_b, out, n);

  // Layer 2: h2 = relu(mean(h1)@Wl + bl + h1@Wr + h1)    -> bufB
  k_agg<1><<<gAgg, 256, 0, stream>>>(out, offs, csr, dis, invd, bufA, n);
  k_gemm_dual<true><<<gG, 256, 0, stream>>>(bufA, out, sage1_lw, sage1_rw, sage1_lb, bufB, n);

  // Layer 3a: t3 = mean(h2)@Wl2 + bl2 + h2@Wr2 + h2      -> d_out
  k_agg<1><<<gAgg, 256, 0, stream>>>(bufB, offs, csr, dis, invd, bufA, n);
  k_gemm_dual<false><<<gG, 256, 0, stream>>>(bufA, bufB, sage2_lw, sage2_rw, sage2_lb, out, n);

  // Layer 3b: h4 = relu(t3 @ lin_w + lin_b)              -> bufB
  k_gemm1<true><<<gG, 256, 0, stream>>>(out, lin_w, lin_b, bufB, n);

  // Layer 4: out = GCNagg(h4) @ gcn2_w + gcn2_b          -> d_out
  k_agg<0><<<gAgg, 256, 0, stream>>>(bufB, offs, csr, dis, invd, bufA, n);
  k_gemm1<false><<<gG, 256, 0, stream>>>(bufA, gcn2_w, gcn2_b, out, n);
}

// Round 2
// 598.280 us; speedup vs baseline: 3.3194x; 3.3194x over previous
//
#include <hip/hip_runtime.h>
#include <stdint.h>

// ---------------------------------------------------------------------------
// GNN forward: GCN -> SAGE(+res) -> SAGE(+res) -> lin -> GCN
// Strategy: aggregate-first (linearity), CSR built once per call (no f32
// atomics in hot path), fused dense 64x64 GEMM epilogues.
// R2 fix: bound tile_mm unroll + __launch_bounds__(256,2). R1's full unroll
// let the scheduler hoist 16x8 float4 LDS loads -> 256 VGPR + ~1.6GB spill
// traffic per GEMM dispatch (730us each).
// ---------------------------------------------------------------------------

__device__ __forceinline__ void fma4(float4& a, float s, const float4& w){
  a.x = fmaf(s, w.x, a.x);
  a.y = fmaf(s, w.y, a.y);
  a.z = fmaf(s, w.z, a.z);
  a.w = fmaf(s, w.w, a.w);
}

// ---------------- CSR build ----------------

__global__ __launch_bounds__(256) void k_deg(const int* __restrict__ dst,
                                             int* __restrict__ deg, int E){
  int i = blockIdx.x * 256 + threadIdx.x;
  if (i < E) atomicAdd(&deg[dst[i]], 1);
}

__global__ __launch_bounds__(256) void k_scanA(const int* __restrict__ deg,
                                               int* __restrict__ bsum, int n){
  __shared__ int sm[256];
  int b = blockIdx.x, t = threadIdx.x;
  int base = b * 1024 + t * 4;
  int s = 0;
  #pragma unroll
  for (int u = 0; u < 4; ++u){ int i = base + u; if (i < n) s += deg[i]; }
  sm[t] = s; __syncthreads();
  for (int off = 128; off > 0; off >>= 1){
    if (t < off) sm[t] += sm[t + off];
    __syncthreads();
  }
  if (t == 0) bsum[b] = sm[0];
}

__global__ void k_scanB(const int* __restrict__ bsum, int* __restrict__ bscan,
                        int* __restrict__ offs, int nb, int n){
  if (blockIdx.x == 0 && threadIdx.x == 0){
    int run = 0;
    for (int i = 0; i < nb; ++i){ bscan[i] = run; run += bsum[i]; }
    offs[n] = run;
  }
}

__global__ __launch_bounds__(256) void k_scanC(const int* __restrict__ deg,
                                               const int* __restrict__ bscan,
                                               int* __restrict__ offs, int n){
  __shared__ int sm[256];
  int b = blockIdx.x, t = threadIdx.x;
  int base = b * 1024 + t * 4;
  int v0 = (base + 0 < n) ? deg[base + 0] : 0;
  int v1 = (base + 1 < n) ? deg[base + 1] : 0;
  int v2 = (base + 2 < n) ? deg[base + 2] : 0;
  int v3 = (base + 3 < n) ? deg[base + 3] : 0;
  int ts = v0 + v1 + v2 + v3;
  sm[t] = ts; __syncthreads();
  #pragma unroll
  for (int off = 1; off < 256; off <<= 1){
    int add = (t >= off) ? sm[t - off] : 0;
    __syncthreads();
    sm[t] += add;
    __syncthreads();
  }
  int excl = sm[t] - ts;
  int run = bscan[b] + excl;
  if (base + 0 < n) offs[base + 0] = run; run += v0;
  if (base + 1 < n) offs[base + 1] = run; run += v1;
  if (base + 2 < n) offs[base + 2] = run; run += v2;
  if (base + 3 < n) offs[base + 3] = run; run += v3;
}

__global__ __launch_bounds__(256) void k_prep(const int* __restrict__ deg,
                                              float* __restrict__ dis,
                                              float* __restrict__ invd, int n){
  int i = blockIdx.x * 256 + threadIdx.x;
  if (i < n){
    float d = (float)deg[i];
    dis[i]  = rsqrtf(d + 1.0f);          // GCN: deg includes self-loop
    invd[i] = 1.0f / fmaxf(d, 1.0f);     // SAGE mean divisor
  }
}

__global__ __launch_bounds__(256) void k_fill(const int* __restrict__ src,
                                              const int* __restrict__ dst,
                                              const int* __restrict__ offs,
                                              int* __restrict__ cnt,
                                              int* __restrict__ csr, int E){
  int e = blockIdx.x * 256 + threadIdx.x;
  if (e < E){
    int d = dst[e];
    int p = offs[d] + atomicAdd(&cnt[d], 1);
    csr[p] = src[e];
  }
}

// ---------------- Aggregation (one wave per node, lane = feature) ----------
// MODE 0: GCN  out[i] = dis[i]*sum_j dis[j]*in[j] + dis[i]^2*in[i]
// MODE 1: SAGE out[i] = (sum_j in[j]) / max(deg,1)

template<int MODE>
__global__ __launch_bounds__(256) void k_agg(const float* __restrict__ in,
                                             const int* __restrict__ offs,
                                             const int* __restrict__ csr,
                                             const float* __restrict__ dis,
                                             const float* __restrict__ invd,
                                             float* __restrict__ out, int n){
  int node = (blockIdx.x * 256 + threadIdx.x) >> 6;
  if (node >= n) return;
  int lane = threadIdx.x & 63;
  int s = offs[node], e = offs[node + 1];
  float acc = 0.f;
  int k = s;
  for (; k + 4 <= e; k += 4){
    int j0 = csr[k], j1 = csr[k+1], j2 = csr[k+2], j3 = csr[k+3];
    float v0 = in[j0*64 + lane];
    float v1 = in[j1*64 + lane];
    float v2 = in[j2*64 + lane];
    float v3 = in[j3*64 + lane];
    if (MODE == 0){
      acc = fmaf(dis[j0], v0, acc);
      acc = fmaf(dis[j1], v1, acc);
      acc = fmaf(dis[j2], v2, acc);
      acc = fmaf(dis[j3], v3, acc);
    } else {
      acc += v0 + v1 + v2 + v3;
    }
  }
  for (; k < e; ++k){
    int j = csr[k];
    float v = in[j*64 + lane];
    acc += (MODE == 0) ? dis[j] * v : v;
  }
  float r;
  if (MODE == 0){
    float di = dis[node];
    r = di * acc + di * di * in[node*64 + lane];
  } else {
    r = acc * invd[node];
  }
  out[node*64 + lane] = r;
}

// ---------------- Dense 64x64 GEMM tiles ----------------
// 256 threads, 64-row tile, each thread computes a 4x4 block.
// A staged row-major in LDS with stride 68 (16B-aligned float4 rows, bank spread).
// k-loop unroll is BOUNDED (see R2 note above) to keep VGPR pressure ~96.

__device__ __forceinline__ void stage_A(const float* __restrict__ A,
                                        float (*As)[68], int row0, int n, int t){
  #pragma unroll
  for (int u = 0; u < 4; ++u){
    int q = u * 256 + t;
    int r = q >> 4;
    int c = (q & 15) * 4;
    int gr = row0 + r;
    float4 v = make_float4(0.f, 0.f, 0.f, 0.f);
    if (gr < n) v = *(const float4*)(A + (size_t)gr * 64 + c);
    *(float4*)&As[r][c] = v;
  }
}

__device__ __forceinline__ void stage_W(const float* __restrict__ W,
                                        float (*Ws)[64], int t){
  #pragma unroll
  for (int u = 0; u < 4; ++u){
    int q = u * 256 + t;
    int r = q >> 4;
    int c = (q & 15) * 4;
    *(float4*)&Ws[r][c] = *(const float4*)(W + r * 64 + c);
  }
}

__device__ __forceinline__ void tile_mm(const float (*As)[68], const float (*Ws)[64],
                                        float4 acc[4], int r0, int c0){
  #pragma unroll 2
  for (int k0 = 0; k0 < 64; k0 += 4){
    float4 a0 = *(const float4*)&As[r0+0][k0];
    float4 a1 = *(const float4*)&As[r0+1][k0];
    float4 a2 = *(const float4*)&As[r0+2][k0];
    float4 a3 = *(const float4*)&As[r0+3][k0];
    float4 w0 = *(const float4*)&Ws[k0+0][c0];
    float4 w1 = *(const float4*)&Ws[k0+1][c0];
    float4 w2 = *(const float4*)&Ws[k0+2][c0];
    float4 w3 = *(const float4*)&Ws[k0+3][c0];
    fma4(acc[0], a0.x, w0); fma4(acc[0], a0.y, w1); fma4(acc[0], a0.z, w2); fma4(acc[0], a0.w, w3);
    fma4(acc[1], a1.x, w0); fma4(acc[1], a1.y, w1); fma4(acc[1], a1.z, w2); fma4(acc[1], a1.w, w3);
    fma4(acc[2], a2.x, w0); fma4(acc[2], a2.y, w1); fma4(acc[2], a2.z, w2); fma4(acc[2], a2.w, w3);
    fma4(acc[3], a3.x, w0); fma4(acc[3], a3.y, w1); fma4(acc[3], a3.z, w2); fma4(acc[3], a3.w, w3);
  }
}

// out = act(A @ W + bias)
template<bool RELU>
__global__ __launch_bounds__(256, 2) void k_gemm1(const float* __restrict__ A,
                                                  const float* __restrict__ W,
                                                  const float* __restrict__ bias,
                                                  float* __restrict__ out, int n){
  __shared__ __align__(16) float As[64][68];
  __shared__ __align__(16) float Ws[64][64];
  int t = threadIdx.x;
  int row0 = blockIdx.x * 64;
  stage_W(W, Ws, t);
  stage_A(A, As, row0, n, t);
  __syncthreads();
  int r0 = (t >> 4) * 4, c0 = (t & 15) * 4;
  float4 b4 = *(const float4*)(bias + c0);
  float4 acc[4] = {b4, b4, b4, b4};
  tile_mm(As, Ws, acc, r0, c0);
  #pragma unroll
  for (int i = 0; i < 4; ++i){
    int gr = row0 + r0 + i;
    if (gr < n){
      float4 v = acc[i];
      if (RELU){
        v.x = fmaxf(v.x, 0.f); v.y = fmaxf(v.y, 0.f);
        v.z = fmaxf(v.z, 0.f); v.w = fmaxf(v.w, 0.f);
      }
      *(float4*)(out + (size_t)gr * 64 + c0) = v;
    }
  }
}

// out = act(A @ W1 + B @ W2 + bias + B)   (SAGE layer with residual)
template<bool RELU>
__global__ __launch_bounds__(256, 2) void k_gemm_dual(const float* __restrict__ A,
                                                      const float* __restrict__ B,
                                                      const float* __restrict__ W1,
                                                      const float* __restrict__ W2,
                                                      const float* __restrict__ bias,
                                                      float* __restrict__ out, int n){
  __shared__ __align__(16) float As[64][68];
  __shared__ __align__(16) float Ws1[64][64];
  __shared__ __align__(16) float Ws2[64][64];
  int t = threadIdx.x;
  int row0 = blockIdx.x * 64;
  stage_W(W1, Ws1, t);
  stage_W(W2, Ws2, t);
  stage_A(A, As, row0, n, t);
  __syncthreads();
  int r0 = (t >> 4) * 4, c0 = (t & 15) * 4;
  float4 b4 = *(const float4*)(bias + c0);
  float4 acc[4] = {b4, b4, b4, b4};
  tile_mm(As, Ws1, acc, r0, c0);
  __syncthreads();
  stage_A(B, As, row0, n, t);
  __syncthreads();
  tile_mm(As, Ws2, acc, r0, c0);
  #pragma unroll
  for (int i = 0; i < 4; ++i){
    float4 res = *(const float4*)&As[r0 + i][c0];   // B tile still in LDS
    acc[i].x += res.x; acc[i].y += res.y; acc[i].z += res.z; acc[i].w += res.w;
    if (RELU){
      acc[i].x = fmaxf(acc[i].x, 0.f); acc[i].y = fmaxf(acc[i].y, 0.f);
      acc[i].z = fmaxf(acc[i].z, 0.f); acc[i].w = fmaxf(acc[i].w, 0.f);
    }
    int gr = row0 + r0 + i;
    if (gr < n) *(float4*)(out + (size_t)gr * 64 + c0) = acc[i];
  }
}

// ---------------------------------------------------------------------------

extern "C" void kernel_launch(void* const* d_in, const int* in_sizes, int n_in,
                              void* d_out, int out_size, void* d_ws, size_t ws_size,
                              hipStream_t stream){
  const float* x        = (const float*)d_in[0];
  const int*   ei       = (const int*)  d_in[1];
  const float* gcn1_w   = (const float*)d_in[2];
  const float* gcn1_b   = (const float*)d_in[3];
  const float* sage1_lw = (const float*)d_in[4];
  const float* sage1_lb = (const float*)d_in[5];
  const float* sage1_rw = (const float*)d_in[6];
  const float* sage2_lw = (const float*)d_in[7];
  const float* sage2_lb = (const float*)d_in[8];
  const float* sage2_rw = (const float*)d_in[9];
  const float* lin_w    = (const float*)d_in[10];
  const float* lin_b    = (const float*)d_in[11];
  const float* gcn2_w   = (const float*)d_in[12];
  const float* gcn2_b   = (const float*)d_in[13];
  float* out = (float*)d_out;

  const int n = in_sizes[0] / 64;
  const int E = in_sizes[1] / 2;
  const int* src = ei;
  const int* dst = ei + E;

  // workspace carve (~58 MB)
  uintptr_t p = (uintptr_t)d_ws;
  auto alloc = [&](size_t b) -> void* {
    p = (p + 255) & ~(uintptr_t)255;
    void* r = (void*)p; p += b; return r;
  };
  float* bufA = (float*)alloc((size_t)n * 64 * 4);
  float* bufB = (float*)alloc((size_t)n * 64 * 4);
  int*   deg  = (int*)  alloc((size_t)n * 4);
  int*   cnt  = (int*)  alloc((size_t)n * 4);
  int*   offs = (int*)  alloc((size_t)(n + 1) * 4);
  const int NB = (n + 1023) / 1024;
  int*   bsum  = (int*) alloc((size_t)NB * 4);
  int*   bscan = (int*) alloc((size_t)NB * 4);
  int*   csr   = (int*) alloc((size_t)E * 4);
  float* dis   = (float*)alloc((size_t)n * 4);
  float* invd  = (float*)alloc((size_t)n * 4);

  hipMemsetAsync(deg, 0, (size_t)n * 4, stream);
  hipMemsetAsync(cnt, 0, (size_t)n * 4, stream);

  const int gE = (E + 255) / 256;
  const int gN = (n + 255) / 256;
  const int gAgg = (n + 3) / 4;      // one wave per node, 4 waves/block
  const int gG = (n + 63) / 64;      // 64-row GEMM tiles

  // CSR build (shared by all 4 aggregation passes)
  k_deg  <<<gE, 256, 0, stream>>>(dst, deg, E);
  k_scanA<<<NB, 256, 0, stream>>>(deg, bsum, n);
  k_scanB<<<1, 1, 0, stream>>>(bsum, bscan, offs, NB, n);
  k_scanC<<<NB, 256, 0, stream>>>(deg, bscan, offs, n);
  k_prep <<<gN, 256, 0, stream>>>(deg, dis, invd, n);
  k_fill <<<gE, 256, 0, stream>>>(src, dst, offs, cnt, csr, E);

  // Layer 1: h1 = relu(GCNagg(x) @ gcn1_w + b)           -> d_out
  k_agg<0><<<gAgg, 256, 0, stream>>>(x, offs, csr, dis, invd, bufA, n);
  k_gemm1<true><<<gG, 256, 0, stream>>>(bufA, gcn1_w, gcn1_b, out, n);

  // Layer 2: h2 = relu(mean(h1)@Wl + bl + h1@Wr + h1)    -> bufB
  k_agg<1><<<gAgg, 256, 0, stream>>>(out, offs, csr, dis, invd, bufA, n);
  k_gemm_dual<true><<<gG, 256, 0, stream>>>(bufA, out, sage1_lw, sage1_rw, sage1_lb, bufB, n);

  // Layer 3a: t3 = mean(h2)@Wl2 + bl2 + h2@Wr2 + h2      -> d_out
  k_agg<1><<<gAgg, 256, 0, stream>>>(bufB, offs, csr, dis, invd, bufA, n);
  k_gemm_dual<false><<<gG, 256, 0, stream>>>(bufA, bufB, sage2_lw, sage2_rw, sage2_lb, out, n);

  // Layer 3b: h4 = relu(t3 @ lin_w + lin_b)              -> bufB
  k_gemm1<true><<<gG, 256, 0, stream>>>(out, lin_w, lin_b, bufB, n);

  // Layer 4: out = GCNagg(h4) @ gcn2_w + gcn2_b          -> d_out
  k_agg<0><<<gAgg, 256, 0, stream>>>(bufB, offs, csr, dis, invd, bufA, n);
  k_gemm1<false><<<gG, 256, 0, stream>>>(bufA, gcn2_w, gcn2_b, out, n);
}

// Round 3
// 571.478 us; speedup vs baseline: 3.4751x; 1.0469x over previous
//
#include <hip/hip_runtime.h>
#include <stdint.h>

// ---------------------------------------------------------------------------
// GNN forward: GCN -> SAGE(+res) -> SAGE(+res) -> lin -> GCN
// Strategy: aggregate-first (linearity), CSR built once per call (no f32
// atomics in hot path), fused dense 64x64 GEMM epilogues.
// R2: bounded unroll + launch_bounds(256,2) fixed GEMM spill (730us -> <20us).
// R3: k_agg quarter-wave float4 gather — 4 neighbor rows per vmem instr,
//     16 rows in flight per wave (was 4). Latency x MLP bound -> ~4x faster.
// ---------------------------------------------------------------------------

__device__ __forceinline__ void fma4(float4& a, float s, const float4& w){
  a.x = fmaf(s, w.x, a.x);
  a.y = fmaf(s, w.y, a.y);
  a.z = fmaf(s, w.z, a.z);
  a.w = fmaf(s, w.w, a.w);
}

// ---------------- CSR build ----------------

__global__ __launch_bounds__(256) void k_deg(const int* __restrict__ dst,
                                             int* __restrict__ deg, int E){
  int i = blockIdx.x * 256 + threadIdx.x;
  if (i < E) atomicAdd(&deg[dst[i]], 1);
}

__global__ __launch_bounds__(256) void k_scanA(const int* __restrict__ deg,
                                               int* __restrict__ bsum, int n){
  __shared__ int sm[256];
  int b = blockIdx.x, t = threadIdx.x;
  int base = b * 1024 + t * 4;
  int s = 0;
  #pragma unroll
  for (int u = 0; u < 4; ++u){ int i = base + u; if (i < n) s += deg[i]; }
  sm[t] = s; __syncthreads();
  for (int off = 128; off > 0; off >>= 1){
    if (t < off) sm[t] += sm[t + off];
    __syncthreads();
  }
  if (t == 0) bsum[b] = sm[0];
}

__global__ void k_scanB(const int* __restrict__ bsum, int* __restrict__ bscan,
                        int* __restrict__ offs, int nb, int n){
  if (blockIdx.x == 0 && threadIdx.x == 0){
    int run = 0;
    for (int i = 0; i < nb; ++i){ bscan[i] = run; run += bsum[i]; }
    offs[n] = run;
  }
}

__global__ __launch_bounds__(256) void k_scanC(const int* __restrict__ deg,
                                               const int* __restrict__ bscan,
                                               int* __restrict__ offs, int n){
  __shared__ int sm[256];
  int b = blockIdx.x, t = threadIdx.x;
  int base = b * 1024 + t * 4;
  int v0 = (base + 0 < n) ? deg[base + 0] : 0;
  int v1 = (base + 1 < n) ? deg[base + 1] : 0;
  int v2 = (base + 2 < n) ? deg[base + 2] : 0;
  int v3 = (base + 3 < n) ? deg[base + 3] : 0;
  int ts = v0 + v1 + v2 + v3;
  sm[t] = ts; __syncthreads();
  #pragma unroll
  for (int off = 1; off < 256; off <<= 1){
    int add = (t >= off) ? sm[t - off] : 0;
    __syncthreads();
    sm[t] += add;
    __syncthreads();
  }
  int excl = sm[t] - ts;
  int run = bscan[b] + excl;
  if (base + 0 < n) offs[base + 0] = run; run += v0;
  if (base + 1 < n) offs[base + 1] = run; run += v1;
  if (base + 2 < n) offs[base + 2] = run; run += v2;
  if (base + 3 < n) offs[base + 3] = run; run += v3;
}

__global__ __launch_bounds__(256) void k_prep(const int* __restrict__ deg,
                                              float* __restrict__ dis,
                                              float* __restrict__ invd, int n){
  int i = blockIdx.x * 256 + threadIdx.x;
  if (i < n){
    float d = (float)deg[i];
    dis[i]  = rsqrtf(d + 1.0f);          // GCN: deg includes self-loop
    invd[i] = 1.0f / fmaxf(d, 1.0f);     // SAGE mean divisor
  }
}

__global__ __launch_bounds__(256) void k_fill(const int* __restrict__ src,
                                              const int* __restrict__ dst,
                                              const int* __restrict__ offs,
                                              int* __restrict__ cnt,
                                              int* __restrict__ csr, int E){
  int e = blockIdx.x * 256 + threadIdx.x;
  if (e < E){
    int d = dst[e];
    int p = offs[d] + atomicAdd(&cnt[d], 1);
    csr[p] = src[e];
  }
}

// ---------------- Aggregation: quarter-wave float4 gather ------------------
// One wave per node. Lane l: group g = l>>4 handles neighbor csr[k+g],
// features (l&15)*4 .. +3 as float4. 16 rows in flight with unroll 4.
// MODE 0: GCN  out[i] = dis[i]*sum_j dis[j]*in[j] + dis[i]^2*in[i]
// MODE 1: SAGE out[i] = (sum_j in[j]) / max(deg,1)

template<int MODE>
__global__ __launch_bounds__(256) void k_agg(const float* __restrict__ in,
                                             const int* __restrict__ offs,
                                             const int* __restrict__ csr,
                                             const float* __restrict__ dis,
                                             const float* __restrict__ invd,
                                             float* __restrict__ out, int n){
  int node = (blockIdx.x * 256 + threadIdx.x) >> 6;
  if (node >= n) return;
  int lane = threadIdx.x & 63;
  int g    = lane >> 4;          // neighbor sub-group 0..3
  int fl   = (lane & 15) * 4;    // feature chunk
  int s = offs[node], e = offs[node + 1];

  float4 acc = make_float4(0.f, 0.f, 0.f, 0.f);
  #pragma unroll 4
  for (int k = s + g; k < e; k += 4){
    int j = csr[k];
    float4 v = *(const float4*)(in + (size_t)j * 64 + fl);
    if (MODE == 0){
      fma4(acc, dis[j], v);
    } else {
      acc.x += v.x; acc.y += v.y; acc.z += v.z; acc.w += v.w;
    }
  }

  // combine the 4 neighbor-groups (lanes l, l+16, l+32, l+48)
  acc.x += __shfl_xor(acc.x, 16); acc.y += __shfl_xor(acc.y, 16);
  acc.z += __shfl_xor(acc.z, 16); acc.w += __shfl_xor(acc.w, 16);
  acc.x += __shfl_xor(acc.x, 32); acc.y += __shfl_xor(acc.y, 32);
  acc.z += __shfl_xor(acc.z, 32); acc.w += __shfl_xor(acc.w, 32);

  if (g == 0){
    float4 r;
    if (MODE == 0){
      float di = dis[node];
      float4 self = *(const float4*)(in + (size_t)node * 64 + fl);
      float d2 = di * di;
      r.x = di * acc.x + d2 * self.x;
      r.y = di * acc.y + d2 * self.y;
      r.z = di * acc.z + d2 * self.z;
      r.w = di * acc.w + d2 * self.w;
    } else {
      float iv = invd[node];
      r.x = acc.x * iv; r.y = acc.y * iv; r.z = acc.z * iv; r.w = acc.w * iv;
    }
    *(float4*)(out + (size_t)node * 64 + fl) = r;
  }
}

// ---------------- Dense 64x64 GEMM tiles ----------------
// 256 threads, 64-row tile, each thread computes a 4x4 block.
// A staged row-major in LDS with stride 68 (16B-aligned float4 rows, bank spread).
// k-loop unroll is BOUNDED to keep VGPR pressure ~96 (R2 fix).

__device__ __forceinline__ void stage_A(const float* __restrict__ A,
                                        float (*As)[68], int row0, int n, int t){
  #pragma unroll
  for (int u = 0; u < 4; ++u){
    int q = u * 256 + t;
    int r = q >> 4;
    int c = (q & 15) * 4;
    int gr = row0 + r;
    float4 v = make_float4(0.f, 0.f, 0.f, 0.f);
    if (gr < n) v = *(const float4*)(A + (size_t)gr * 64 + c);
    *(float4*)&As[r][c] = v;
  }
}

__device__ __forceinline__ void stage_W(const float* __restrict__ W,
                                        float (*Ws)[64], int t){
  #pragma unroll
  for (int u = 0; u < 4; ++u){
    int q = u * 256 + t;
    int r = q >> 4;
    int c = (q & 15) * 4;
    *(float4*)&Ws[r][c] = *(const float4*)(W + r * 64 + c);
  }
}

__device__ __forceinline__ void tile_mm(const float (*As)[68], const float (*Ws)[64],
                                        float4 acc[4], int r0, int c0){
  #pragma unroll 2
  for (int k0 = 0; k0 < 64; k0 += 4){
    float4 a0 = *(const float4*)&As[r0+0][k0];
    float4 a1 = *(const float4*)&As[r0+1][k0];
    float4 a2 = *(const float4*)&As[r0+2][k0];
    float4 a3 = *(const float4*)&As[r0+3][k0];
    float4 w0 = *(const float4*)&Ws[k0+0][c0];
    float4 w1 = *(const float4*)&Ws[k0+1][c0];
    float4 w2 = *(const float4*)&Ws[k0+2][c0];
    float4 w3 = *(const float4*)&Ws[k0+3][c0];
    fma4(acc[0], a0.x, w0); fma4(acc[0], a0.y, w1); fma4(acc[0], a0.z, w2); fma4(acc[0], a0.w, w3);
    fma4(acc[1], a1.x, w0); fma4(acc[1], a1.y, w1); fma4(acc[1], a1.z, w2); fma4(acc[1], a1.w, w3);
    fma4(acc[2], a2.x, w0); fma4(acc[2], a2.y, w1); fma4(acc[2], a2.z, w2); fma4(acc[2], a2.w, w3);
    fma4(acc[3], a3.x, w0); fma4(acc[3], a3.y, w1); fma4(acc[3], a3.z, w2); fma4(acc[3], a3.w, w3);
  }
}

// out = act(A @ W + bias)
template<bool RELU>
__global__ __launch_bounds__(256, 2) void k_gemm1(const float* __restrict__ A,
                                                  const float* __restrict__ W,
                                                  const float* __restrict__ bias,
                                                  float* __restrict__ out, int n){
  __shared__ __align__(16) float As[64][68];
  __shared__ __align__(16) float Ws[64][64];
  int t = threadIdx.x;
  int row0 = blockIdx.x * 64;
  stage_W(W, Ws, t);
  stage_A(A, As, row0, n, t);
  __syncthreads();
  int r0 = (t >> 4) * 4, c0 = (t & 15) * 4;
  float4 b4 = *(const float4*)(bias + c0);
  float4 acc[4] = {b4, b4, b4, b4};
  tile_mm(As, Ws, acc, r0, c0);
  #pragma unroll
  for (int i = 0; i < 4; ++i){
    int gr = row0 + r0 + i;
    if (gr < n){
      float4 v = acc[i];
      if (RELU){
        v.x = fmaxf(v.x, 0.f); v.y = fmaxf(v.y, 0.f);
        v.z = fmaxf(v.z, 0.f); v.w = fmaxf(v.w, 0.f);
      }
      *(float4*)(out + (size_t)gr * 64 + c0) = v;
    }
  }
}

// out = act(A @ W1 + B @ W2 + bias + B)   (SAGE layer with residual)
template<bool RELU>
__global__ __launch_bounds__(256, 2) void k_gemm_dual(const float* __restrict__ A,
                                                      const float* __restrict__ B,
                                                      const float* __restrict__ W1,
                                                      const float* __restrict__ W2,
                                                      const float* __restrict__ bias,
                                                      float* __restrict__ out, int n){
  __shared__ __align__(16) float As[64][68];
  __shared__ __align__(16) float Ws1[64][64];
  __shared__ __align__(16) float Ws2[64][64];
  int t = threadIdx.x;
  int row0 = blockIdx.x * 64;
  stage_W(W1, Ws1, t);
  stage_W(W2, Ws2, t);
  stage_A(A, As, row0, n, t);
  __syncthreads();
  int r0 = (t >> 4) * 4, c0 = (t & 15) * 4;
  float4 b4 = *(const float4*)(bias + c0);
  float4 acc[4] = {b4, b4, b4, b4};
  tile_mm(As, Ws1, acc, r0, c0);
  __syncthreads();
  stage_A(B, As, row0, n, t);
  __syncthreads();
  tile_mm(As, Ws2, acc, r0, c0);
  #pragma unroll
  for (int i = 0; i < 4; ++i){
    float4 res = *(const float4*)&As[r0 + i][c0];   // B tile still in LDS
    acc[i].x += res.x; acc[i].y += res.y; acc[i].z += res.z; acc[i].w += res.w;
    if (RELU){
      acc[i].x = fmaxf(acc[i].x, 0.f); acc[i].y = fmaxf(acc[i].y, 0.f);
      acc[i].z = fmaxf(acc[i].z, 0.f); acc[i].w = fmaxf(acc[i].w, 0.f);
    }
    int gr = row0 + r0 + i;
    if (gr < n) *(float4*)(out + (size_t)gr * 64 + c0) = acc[i];
  }
}

// ---------------------------------------------------------------------------

extern "C" void kernel_launch(void* const* d_in, const int* in_sizes, int n_in,
                              void* d_out, int out_size, void* d_ws, size_t ws_size,
                              hipStream_t stream){
  const float* x        = (const float*)d_in[0];
  const int*   ei       = (const int*)  d_in[1];
  const float* gcn1_w   = (const float*)d_in[2];
  const float* gcn1_b   = (const float*)d_in[3];
  const float* sage1_lw = (const float*)d_in[4];
  const float* sage1_lb = (const float*)d_in[5];
  const float* sage1_rw = (const float*)d_in[6];
  const float* sage2_lw = (const float*)d_in[7];
  const float* sage2_lb = (const float*)d_in[8];
  const float* sage2_rw = (const float*)d_in[9];
  const float* lin_w    = (const float*)d_in[10];
  const float* lin_b    = (const float*)d_in[11];
  const float* gcn2_w   = (const float*)d_in[12];
  const float* gcn2_b   = (const float*)d_in[13];
  float* out = (float*)d_out;

  const int n = in_sizes[0] / 64;
  const int E = in_sizes[1] / 2;
  const int* src = ei;
  const int* dst = ei + E;

  // workspace carve (~58 MB)
  uintptr_t p = (uintptr_t)d_ws;
  auto alloc = [&](size_t b) -> void* {
    p = (p + 255) & ~(uintptr_t)255;
    void* r = (void*)p; p += b; return r;
  };
  float* bufA = (float*)alloc((size_t)n * 64 * 4);
  float* bufB = (float*)alloc((size_t)n * 64 * 4);
  int*   deg  = (int*)  alloc((size_t)n * 4);
  int*   cnt  = (int*)  alloc((size_t)n * 4);
  int*   offs = (int*)  alloc((size_t)(n + 1) * 4);
  const int NB = (n + 1023) / 1024;
  int*   bsum  = (int*) alloc((size_t)NB * 4);
  int*   bscan = (int*) alloc((size_t)NB * 4);
  int*   csr   = (int*) alloc((size_t)E * 4);
  float* dis   = (float*)alloc((size_t)n * 4);
  float* invd  = (float*)alloc((size_t)n * 4);

  hipMemsetAsync(deg, 0, (size_t)n * 4, stream);
  hipMemsetAsync(cnt, 0, (size_t)n * 4, stream);

  const int gE = (E + 255) / 256;
  const int gN = (n + 255) / 256;
  const int gAgg = (n + 3) / 4;      // one wave per node, 4 waves/block
  const int gG = (n + 63) / 64;      // 64-row GEMM tiles

  // CSR build (shared by all 4 aggregation passes)
  k_deg  <<<gE, 256, 0, stream>>>(dst, deg, E);
  k_scanA<<<NB, 256, 0, stream>>>(deg, bsum, n);
  k_scanB<<<1, 1, 0, stream>>>(bsum, bscan, offs, NB, n);
  k_scanC<<<NB, 256, 0, stream>>>(deg, bscan, offs, n);
  k_prep <<<gN, 256, 0, stream>>>(deg, dis, invd, n);
  k_fill <<<gE, 256, 0, stream>>>(src, dst, offs, cnt, csr, E);

  // Layer 1: h1 = relu(GCNagg(x) @ gcn1_w + b)           -> d_out
  k_agg<0><<<gAgg, 256, 0, stream>>>(x, offs, csr, dis, invd, bufA, n);
  k_gemm1<true><<<gG, 256, 0, stream>>>(bufA, gcn1_w, gcn1_b, out, n);

  // Layer 2: h2 = relu(mean(h1)@Wl + bl + h1@Wr + h1)    -> bufB
  k_agg<1><<<gAgg, 256, 0, stream>>>(out, offs, csr, dis, invd, bufA, n);
  k_gemm_dual<true><<<gG, 256, 0, stream>>>(bufA, out, sage1_lw, sage1_rw, sage1_lb, bufB, n);

  // Layer 3a: t3 = mean(h2)@Wl2 + bl2 + h2@Wr2 + h2      -> d_out
  k_agg<1><<<gAgg, 256, 0, stream>>>(bufB, offs, csr, dis, invd, bufA, n);
  k_gemm_dual<false><<<gG, 256, 0, stream>>>(bufA, bufB, sage2_lw, sage2_rw, sage2_lb, out, n);

  // Layer 3b: h4 = relu(t3 @ lin_w + lin_b)              -> bufB
  k_gemm1<true><<<gG, 256, 0, stream>>>(out, lin_w, lin_b, bufB, n);

  // Layer 4: out = GCNagg(h4) @ gcn2_w + gcn2_b          -> d_out
  k_agg<0><<<gAgg, 256, 0, stream>>>(bufB, offs, csr, dis, invd, bufA, n);
  k_gemm1<false><<<gG, 256, 0, stream>>>(bufA, gcn2_w, gcn2_b, out, n);
}

// Round 4
// 545.397 us; speedup vs baseline: 3.6412x; 1.0478x over previous
//
#include <hip/hip_runtime.h>
#include <hip/hip_fp16.h>
#include <stdint.h>

// ---------------------------------------------------------------------------
// GNN forward: GCN -> SAGE(+res) -> SAGE(+res) -> lin -> GCN
// Strategy: aggregate-first (linearity), CSR built once per call, fused dense
// 64x64 GEMM epilogues.
// R2: bounded unroll + launch_bounds(256,2) fixed GEMM spill.
// R3: quarter-wave float4 gather (16 rows in flight/wave).
// R4a: XCD-sliced k_deg/k_fill — each XCD-group (bid&7) owns a node slice;
//      csr/cnt lines live in ONE L2, kill write-allocate thrash (88MB->~12MB).
// R4b: fp16 gather mirror — agg reads 128B rows instead of 256B (tolerance is
//      bf16-grade; fp16 rel err ~5e-4 is safe).
// ---------------------------------------------------------------------------

__device__ __forceinline__ void fma4(float4& a, float s, const float4& w){
  a.x = fmaf(s, w.x, a.x);
  a.y = fmaf(s, w.y, a.y);
  a.z = fmaf(s, w.z, a.z);
  a.w = fmaf(s, w.w, a.w);
}

__device__ __forceinline__ ushort4 pack_h4(float4 v){
  ushort4 u;
  u.x = __half_as_ushort(__float2half(v.x));
  u.y = __half_as_ushort(__float2half(v.y));
  u.z = __half_as_ushort(__float2half(v.z));
  u.w = __half_as_ushort(__float2half(v.w));
  return u;
}

__device__ __forceinline__ float4 unpack_h4(ushort4 u){
  return make_float4(__half2float(__ushort_as_half(u.x)),
                     __half2float(__ushort_as_half(u.y)),
                     __half2float(__ushort_as_half(u.z)),
                     __half2float(__ushort_as_half(u.w)));
}

// ---------------- CSR build (XCD-sliced scatter) ----------------
// Blocks with equal (bid & 7) dispatch to the same XCD (round-robin heuristic;
// correctness does not depend on it). Group g owns nodes [g*SL, min(n,(g+1)*SL)).
// Each group scans ALL edges, filters by dst-slice -> cnt/csr slice is cached
// in exactly one XCD L2, lines fill completely before writeback.

#define FILL_BLOCKS 1024   // 128 blocks per XCD-group

__global__ __launch_bounds__(256) void k_deg(const int* __restrict__ dst,
                                             int* __restrict__ deg, int E, int n){
  int s  = blockIdx.x & 7;
  int q  = blockIdx.x >> 3;
  const int NQ = FILL_BLOCKS / 8;
  int SL = (n + 7) / 8;
  int lo = s * SL, hi = min(n, lo + SL);
  int chunk = (E + NQ - 1) / NQ;
  int e0 = q * chunk, e1 = min(E, e0 + chunk);
  for (int e = e0 + threadIdx.x; e < e1; e += 256){
    int d = dst[e];
    if (d >= lo && d < hi) atomicAdd(&deg[d], 1);
  }
}

__global__ __launch_bounds__(256) void k_fill(const int* __restrict__ src,
                                              const int* __restrict__ dst,
                                              const int* __restrict__ offs,
                                              int* __restrict__ cnt,
                                              int* __restrict__ csr, int E, int n){
  int s  = blockIdx.x & 7;
  int q  = blockIdx.x >> 3;
  const int NQ = FILL_BLOCKS / 8;
  int SL = (n + 7) / 8;
  int lo = s * SL, hi = min(n, lo + SL);
  int chunk = (E + NQ - 1) / NQ;
  int e0 = q * chunk, e1 = min(E, e0 + chunk);
  for (int e = e0 + threadIdx.x; e < e1; e += 256){
    int d = dst[e];
    if (d >= lo && d < hi){
      int p = offs[d] + atomicAdd(&cnt[d], 1);
      csr[p] = src[e];
    }
  }
}

// ---------------- scans / prep (unchanged, tiny) ----------------

__global__ __launch_bounds__(256) void k_scanA(const int* __restrict__ deg,
                                               int* __restrict__ bsum, int n){
  __shared__ int sm[256];
  int b = blockIdx.x, t = threadIdx.x;
  int base = b * 1024 + t * 4;
  int s = 0;
  #pragma unroll
  for (int u = 0; u < 4; ++u){ int i = base + u; if (i < n) s += deg[i]; }
  sm[t] = s; __syncthreads();
  for (int off = 128; off > 0; off >>= 1){
    if (t < off) sm[t] += sm[t + off];
    __syncthreads();
  }
  if (t == 0) bsum[b] = sm[0];
}

__global__ void k_scanB(const int* __restrict__ bsum, int* __restrict__ bscan,
                        int* __restrict__ offs, int nb, int n){
  if (blockIdx.x == 0 && threadIdx.x == 0){
    int run = 0;
    for (int i = 0; i < nb; ++i){ bscan[i] = run; run += bsum[i]; }
    offs[n] = run;
  }
}

__global__ __launch_bounds__(256) void k_scanC(const int* __restrict__ deg,
                                               const int* __restrict__ bscan,
                                               int* __restrict__ offs, int n){
  __shared__ int sm[256];
  int b = blockIdx.x, t = threadIdx.x;
  int base = b * 1024 + t * 4;
  int v0 = (base + 0 < n) ? deg[base + 0] : 0;
  int v1 = (base + 1 < n) ? deg[base + 1] : 0;
  int v2 = (base + 2 < n) ? deg[base + 2] : 0;
  int v3 = (base + 3 < n) ? deg[base + 3] : 0;
  int ts = v0 + v1 + v2 + v3;
  sm[t] = ts; __syncthreads();
  #pragma unroll
  for (int off = 1; off < 256; off <<= 1){
    int add = (t >= off) ? sm[t - off] : 0;
    __syncthreads();
    sm[t] += add;
    __syncthreads();
  }
  int excl = sm[t] - ts;
  int run = bscan[b] + excl;
  if (base + 0 < n) offs[base + 0] = run; run += v0;
  if (base + 1 < n) offs[base + 1] = run; run += v1;
  if (base + 2 < n) offs[base + 2] = run; run += v2;
  if (base + 3 < n) offs[base + 3] = run; run += v3;
}

__global__ __launch_bounds__(256) void k_prep(const int* __restrict__ deg,
                                              float* __restrict__ dis,
                                              float* __restrict__ invd, int n){
  int i = blockIdx.x * 256 + threadIdx.x;
  if (i < n){
    float d = (float)deg[i];
    dis[i]  = rsqrtf(d + 1.0f);          // GCN: deg includes self-loop
    invd[i] = 1.0f / fmaxf(d, 1.0f);     // SAGE mean divisor
  }
}

// ---------------- fp32 -> fp16 convert (for layer-1 gather of x) -----------

__global__ __launch_bounds__(256) void k_f2h(const float* __restrict__ in,
                                             ushort* __restrict__ out, int n4){
  int i = blockIdx.x * 256 + threadIdx.x;
  if (i < n4){
    float4 v = ((const float4*)in)[i];
    ((ushort4*)out)[i] = pack_h4(v);
  }
}

// ---------------- Aggregation: quarter-wave fp16 gather --------------------
// One wave per node. Lane l: group g=l>>4 handles neighbor csr[k+g], features
// (l&15)*4..+3 as ushort4 (8B). Row = 128B. 16 rows in flight with unroll 4.
// MODE 0: GCN  out[i] = dis[i]*sum_j dis[j]*in[j] + dis[i]^2*in[i]
// MODE 1: SAGE out[i] = (sum_j in[j]) / max(deg,1)

template<int MODE>
__global__ __launch_bounds__(256) void k_agg(const ushort* __restrict__ in,
                                             const int* __restrict__ offs,
                                             const int* __restrict__ csr,
                                             const float* __restrict__ dis,
                                             const float* __restrict__ invd,
                                             float* __restrict__ out, int n){
  int node = (blockIdx.x * 256 + threadIdx.x) >> 6;
  if (node >= n) return;
  int lane = threadIdx.x & 63;
  int g    = lane >> 4;          // neighbor sub-group 0..3
  int fl   = (lane & 15) * 4;    // feature chunk
  int s = offs[node], e = offs[node + 1];

  float4 acc = make_float4(0.f, 0.f, 0.f, 0.f);
  #pragma unroll 4
  for (int k = s + g; k < e; k += 4){
    int j = csr[k];
    float4 v = unpack_h4(*(const ushort4*)(in + (size_t)j * 64 + fl));
    if (MODE == 0){
      fma4(acc, dis[j], v);
    } else {
      acc.x += v.x; acc.y += v.y; acc.z += v.z; acc.w += v.w;
    }
  }

  // combine the 4 neighbor-groups (lanes l, l+16, l+32, l+48)
  acc.x += __shfl_xor(acc.x, 16); acc.y += __shfl_xor(acc.y, 16);
  acc.z += __shfl_xor(acc.z, 16); acc.w += __shfl_xor(acc.w, 16);
  acc.x += __shfl_xor(acc.x, 32); acc.y += __shfl_xor(acc.y, 32);
  acc.z += __shfl_xor(acc.z, 32); acc.w += __shfl_xor(acc.w, 32);

  if (g == 0){
    float4 r;
    if (MODE == 0){
      float di = dis[node];
      float4 self = unpack_h4(*(const ushort4*)(in + (size_t)node * 64 + fl));
      float d2 = di * di;
      r.x = di * acc.x + d2 * self.x;
      r.y = di * acc.y + d2 * self.y;
      r.z = di * acc.z + d2 * self.z;
      r.w = di * acc.w + d2 * self.w;
    } else {
      float iv = invd[node];
      r.x = acc.x * iv; r.y = acc.y * iv; r.z = acc.z * iv; r.w = acc.w * iv;
    }
    *(float4*)(out + (size_t)node * 64 + fl) = r;
  }
}

// ---------------- Dense 64x64 GEMM tiles ----------------
// 256 threads, 64-row tile, each thread computes a 4x4 block. Bounded unroll
// (R2). Epilogues optionally mirror the output to fp16 for the next gather.

__device__ __forceinline__ void stage_A(const float* __restrict__ A,
                                        float (*As)[68], int row0, int n, int t){
  #pragma unroll
  for (int u = 0; u < 4; ++u){
    int q = u * 256 + t;
    int r = q >> 4;
    int c = (q & 15) * 4;
    int gr = row0 + r;
    float4 v = make_float4(0.f, 0.f, 0.f, 0.f);
    if (gr < n) v = *(const float4*)(A + (size_t)gr * 64 + c);
    *(float4*)&As[r][c] = v;
  }
}

__device__ __forceinline__ void stage_W(const float* __restrict__ W,
                                        float (*Ws)[64], int t){
  #pragma unroll
  for (int u = 0; u < 4; ++u){
    int q = u * 256 + t;
    int r = q >> 4;
    int c = (q & 15) * 4;
    *(float4*)&Ws[r][c] = *(const float4*)(W + r * 64 + c);
  }
}

__device__ __forceinline__ void tile_mm(const float (*As)[68], const float (*Ws)[64],
                                        float4 acc[4], int r0, int c0){
  #pragma unroll 2
  for (int k0 = 0; k0 < 64; k0 += 4){
    float4 a0 = *(const float4*)&As[r0+0][k0];
    float4 a1 = *(const float4*)&As[r0+1][k0];
    float4 a2 = *(const float4*)&As[r0+2][k0];
    float4 a3 = *(const float4*)&As[r0+3][k0];
    float4 w0 = *(const float4*)&Ws[k0+0][c0];
    float4 w1 = *(const float4*)&Ws[k0+1][c0];
    float4 w2 = *(const float4*)&Ws[k0+2][c0];
    float4 w3 = *(const float4*)&Ws[k0+3][c0];
    fma4(acc[0], a0.x, w0); fma4(acc[0], a0.y, w1); fma4(acc[0], a0.z, w2); fma4(acc[0], a0.w, w3);
    fma4(acc[1], a1.x, w0); fma4(acc[1], a1.y, w1); fma4(acc[1], a1.z, w2); fma4(acc[1], a1.w, w3);
    fma4(acc[2], a2.x, w0); fma4(acc[2], a2.y, w1); fma4(acc[2], a2.z, w2); fma4(acc[2], a2.w, w3);
    fma4(acc[3], a3.x, w0); fma4(acc[3], a3.y, w1); fma4(acc[3], a3.z, w2); fma4(acc[3], a3.w, w3);
  }
}

// out = act(A @ W + bias)  [+ fp16 mirror if outh != nullptr]
template<bool RELU>
__global__ __launch_bounds__(256, 2) void k_gemm1(const float* __restrict__ A,
                                                  const float* __restrict__ W,
                                                  const float* __restrict__ bias,
                                                  float* __restrict__ out,
                                                  ushort* __restrict__ outh, int n){
  __shared__ __align__(16) float As[64][68];
  __shared__ __align__(16) float Ws[64][64];
  int t = threadIdx.x;
  int row0 = blockIdx.x * 64;
  stage_W(W, Ws, t);
  stage_A(A, As, row0, n, t);
  __syncthreads();
  int r0 = (t >> 4) * 4, c0 = (t & 15) * 4;
  float4 b4 = *(const float4*)(bias + c0);
  float4 acc[4] = {b4, b4, b4, b4};
  tile_mm(As, Ws, acc, r0, c0);
  #pragma unroll
  for (int i = 0; i < 4; ++i){
    int gr = row0 + r0 + i;
    if (gr < n){
      float4 v = acc[i];
      if (RELU){
        v.x = fmaxf(v.x, 0.f); v.y = fmaxf(v.y, 0.f);
        v.z = fmaxf(v.z, 0.f); v.w = fmaxf(v.w, 0.f);
      }
      *(float4*)(out + (size_t)gr * 64 + c0) = v;
      if (outh) *(ushort4*)(outh + (size_t)gr * 64 + c0) = pack_h4(v);
    }
  }
}

// out = act(A @ W1 + B @ W2 + bias + B)   (SAGE layer with residual)
template<bool RELU>
__global__ __launch_bounds__(256, 2) void k_gemm_dual(const float* __restrict__ A,
                                                      const float* __restrict__ B,
                                                      const float* __restrict__ W1,
                                                      const float* __restrict__ W2,
                                                      const float* __restrict__ bias,
                                                      float* __restrict__ out,
                                                      ushort* __restrict__ outh, int n){
  __shared__ __align__(16) float As[64][68];
  __shared__ __align__(16) float Ws1[64][64];
  __shared__ __align__(16) float Ws2[64][64];
  int t = threadIdx.x;
  int row0 = blockIdx.x * 64;
  stage_W(W1, Ws1, t);
  stage_W(W2, Ws2, t);
  stage_A(A, As, row0, n, t);
  __syncthreads();
  int r0 = (t >> 4) * 4, c0 = (t & 15) * 4;
  float4 b4 = *(const float4*)(bias + c0);
  float4 acc[4] = {b4, b4, b4, b4};
  tile_mm(As, Ws1, acc, r0, c0);
  __syncthreads();
  stage_A(B, As, row0, n, t);
  __syncthreads();
  tile_mm(As, Ws2, acc, r0, c0);
  #pragma unroll
  for (int i = 0; i < 4; ++i){
    float4 res = *(const float4*)&As[r0 + i][c0];   // B tile still in LDS
    acc[i].x += res.x; acc[i].y += res.y; acc[i].z += res.z; acc[i].w += res.w;
    if (RELU){
      acc[i].x = fmaxf(acc[i].x, 0.f); acc[i].y = fmaxf(acc[i].y, 0.f);
      acc[i].z = fmaxf(acc[i].z, 0.f); acc[i].w = fmaxf(acc[i].w, 0.f);
    }
    int gr = row0 + r0 + i;
    if (gr < n){
      *(float4*)(out + (size_t)gr * 64 + c0) = acc[i];
      if (outh) *(ushort4*)(outh + (size_t)gr * 64 + c0) = pack_h4(acc[i]);
    }
  }
}

// ---------------------------------------------------------------------------

extern "C" void kernel_launch(void* const* d_in, const int* in_sizes, int n_in,
                              void* d_out, int out_size, void* d_ws, size_t ws_size,
                              hipStream_t stream){
  const float* x        = (const float*)d_in[0];
  const int*   ei       = (const int*)  d_in[1];
  const float* gcn1_w   = (const float*)d_in[2];
  const float* gcn1_b   = (const float*)d_in[3];
  const float* sage1_lw = (const float*)d_in[4];
  const float* sage1_lb = (const float*)d_in[5];
  const float* sage1_rw = (const float*)d_in[6];
  const float* sage2_lw = (const float*)d_in[7];
  const float* sage2_lb = (const float*)d_in[8];
  const float* sage2_rw = (const float*)d_in[9];
  const float* lin_w    = (const float*)d_in[10];
  const float* lin_b    = (const float*)d_in[11];
  const float* gcn2_w   = (const float*)d_in[12];
  const float* gcn2_b   = (const float*)d_in[13];
  float* out = (float*)d_out;

  const int n = in_sizes[0] / 64;
  const int E = in_sizes[1] / 2;
  const int* src = ei;
  const int* dst = ei + E;

  // workspace carve (~71 MB)
  uintptr_t p = (uintptr_t)d_ws;
  auto alloc = [&](size_t b) -> void* {
    p = (p + 255) & ~(uintptr_t)255;
    void* r = (void*)p; p += b; return r;
  };
  float*  bufA = (float*)alloc((size_t)n * 64 * 4);
  float*  bufB = (float*)alloc((size_t)n * 64 * 4);
  ushort* hh   = (ushort*)alloc((size_t)n * 64 * 2);  // fp16 gather mirror (reused)
  int*    deg  = (int*)  alloc((size_t)n * 4);
  int*    cnt  = (int*)  alloc((size_t)n * 4);
  int*    offs = (int*)  alloc((size_t)(n + 1) * 4);
  const int NB = (n + 1023) / 1024;
  int*    bsum  = (int*) alloc((size_t)NB * 4);
  int*    bscan = (int*) alloc((size_t)NB * 4);
  int*    csr   = (int*) alloc((size_t)E * 4);
  float*  dis   = (float*)alloc((size_t)n * 4);
  float*  invd  = (float*)alloc((size_t)n * 4);

  hipMemsetAsync(deg, 0, (size_t)n * 4, stream);
  hipMemsetAsync(cnt, 0, (size_t)n * 4, stream);

  const int gN = (n + 255) / 256;
  const int gAgg = (n + 3) / 4;      // one wave per node, 4 waves/block
  const int gG = (n + 63) / 64;      // 64-row GEMM tiles
  const int gC = (n * 16 + 255) / 256;

  // CSR build (XCD-sliced; shared by all 4 aggregation passes)
  k_deg  <<<FILL_BLOCKS, 256, 0, stream>>>(dst, deg, E, n);
  k_scanA<<<NB, 256, 0, stream>>>(deg, bsum, n);
  k_scanB<<<1, 1, 0, stream>>>(bsum, bscan, offs, NB, n);
  k_scanC<<<NB, 256, 0, stream>>>(deg, bscan, offs, n);
  k_prep <<<gN, 256, 0, stream>>>(deg, dis, invd, n);
  k_fill <<<FILL_BLOCKS, 256, 0, stream>>>(src, dst, offs, cnt, csr, E, n);

  // Layer 1: h1 = relu(GCNagg(x) @ gcn1_w + b)           -> d_out (+hh)
  k_f2h<<<gC, 256, 0, stream>>>(x, hh, n * 16);
  k_agg<0><<<gAgg, 256, 0, stream>>>(hh, offs, csr, dis, invd, bufA, n);
  k_gemm1<true><<<gG, 256, 0, stream>>>(bufA, gcn1_w, gcn1_b, out, hh, n);

  // Layer 2: h2 = relu(mean(h1)@Wl + bl + h1@Wr + h1)    -> bufB (+hh)
  k_agg<1><<<gAgg, 256, 0, stream>>>(hh, offs, csr, dis, invd, bufA, n);
  k_gemm_dual<true><<<gG, 256, 0, stream>>>(bufA, out, sage1_lw, sage1_rw, sage1_lb, bufB, hh, n);

  // Layer 3a: t3 = mean(h2)@Wl2 + bl2 + h2@Wr2 + h2      -> d_out
  k_agg<1><<<gAgg, 256, 0, stream>>>(hh, offs, csr, dis, invd, bufA, n);
  k_gemm_dual<false><<<gG, 256, 0, stream>>>(bufA, bufB, sage2_lw, sage2_rw, sage2_lb, out, (ushort*)nullptr, n);

  // Layer 3b: h4 = relu(t3 @ lin_w + lin_b)              -> bufB (+hh)
  k_gemm1<true><<<gG, 256, 0, stream>>>(out, lin_w, lin_b, bufB, hh, n);

  // Layer 4: out = GCNagg(h4) @ gcn2_w + gcn2_b          -> d_out
  k_agg<0><<<gAgg, 256, 0, stream>>>(hh, offs, csr, dis, invd, bufA, n);
  k_gemm1<false><<<gG, 256, 0, stream>>>(bufA, gcn2_w, gcn2_b, out, (ushort*)nullptr, n);
}